// Round 5
// baseline (145.128 us; speedup 1.0000x reference)
//
#include <hip/hip_runtime.h>

#define FRAME 160
#define ORDER 16
#define LPC_EPS 1e-8f
#define NF 32        // frames per block (8 frames per wave)
#define BS 256       // threads per block (4 waves); 8 threads per frame
#define SEG 20       // samples per part
#define SX 164       // padded LDS row stride in floats (+4-float bank skew)
#define QPB (NF * FRAME / 4 / BS)  // 5 float4 iterations per thread stage-in/out

// One block = 32 frames. LDS 20,992 B. Phases:
//   stage-in -> W[52] window to regs -> autocorr partials -> partials OVERLAID
//   into own frame's LDS row (row is dead: frame-private + intra-wave DS order)
//   -> barrier -> Levinson ONCE per frame (lane t<32), coeffs into row head
//   -> barrier -> coeff broadcast-read -> FIR -> in-place row write -> stage-out.
// Levinson redundancy (was 8x) and the 51-op shfl butterfly are gone.
__global__ __launch_bounds__(BS, 4) void lpc_fused(const float* __restrict__ x,
                                                   float* __restrict__ out) {
    __shared__ float xs[NF * SX];  // 20,992 B

    const int t = threadIdx.x;
    const long long base = (long long)blockIdx.x * (NF * FRAME);

    // ---- stage in: 1280 consecutive float4, fully coalesced ----
#pragma unroll
    for (int it = 0; it < QPB; ++it) {
        int p = it * BS + t;              // quad index within block [0,1280)
        int f = p / 40;                   // 40 quads per frame
        int off = (p - f * 40) * 4;
        float4 v = *(const float4*)(x + base + 4 * p);
        *(float4*)(&xs[f * SX + off]) = v;
    }
    __syncthreads();

    const int fi = t >> 3;       // frame within block [0,32)
    const int part = t & 7;      // n-range: [20*part, 20*part+20)
    const int sbase = SEG * part;

    // ---- combined window W[j] = x[sbase-16+j], j in [0,52), zero-padded ----
    float W[52];
#pragma unroll
    for (int m = 0; m < 13; ++m) {
        int idx = sbase - 16 + 4 * m;    // multiple of 4; frame bounds are too
        float4 v = make_float4(0.f, 0.f, 0.f, 0.f);
        if (idx >= 0 && idx < FRAME) v = *(const float4*)(&xs[fi * SX + idx]);
        W[4 * m + 0] = v.x; W[4 * m + 1] = v.y;
        W[4 * m + 2] = v.z; W[4 * m + 3] = v.w;
    }

    // ---- partial autocorrelation: r[k] = sum_{n=0..19} W[16+n]*W[16+n+k] ----
    float r[ORDER + 1];
#pragma unroll
    for (int k = 0; k <= ORDER; ++k) r[k] = 0.f;
#pragma unroll
    for (int n = 0; n < SEG; ++n) {
#pragma unroll
        for (int k = 0; k <= ORDER; ++k) {
            r[k] = fmaf(W[16 + n], W[16 + n + k], r[k]);
        }
    }

    // ---- overlay partials into own frame row (frame-private; the row's x-data
    //      was fully consumed by this wave's W loads, DS ops are in-order) ----
    {
        float* slot = &xs[fi * SX + part * SEG];
#pragma unroll
        for (int m = 0; m < 4; ++m)
            *(float4*)(slot + 4 * m) =
                make_float4(r[4 * m], r[4 * m + 1], r[4 * m + 2], r[4 * m + 3]);
        slot[16] = r[16];
    }
    __syncthreads();

    // ---- Levinson-Durbin, ONCE per frame (wave 0, lanes 0..31) ----
    if (t < NF) {
        float rr[ORDER + 1];
#pragma unroll
        for (int k = 0; k <= ORDER; ++k) rr[k] = 0.f;
#pragma unroll
        for (int p = 0; p < 8; ++p) {
            const float* slot = &xs[t * SX + p * SEG];
#pragma unroll
            for (int m = 0; m < 4; ++m) {
                float4 v = *(const float4*)(slot + 4 * m);
                rr[4 * m + 0] += v.x; rr[4 * m + 1] += v.y;
                rr[4 * m + 2] += v.z; rr[4 * m + 3] += v.w;
            }
            rr[16] += slot[16];
        }

        float a[ORDER + 1];
        a[0] = 1.f;
#pragma unroll
        for (int j = 1; j <= ORDER; ++j) a[j] = 0.f;
        float e = (rr[0] != 0.f) ? rr[0] : LPC_EPS;  // e >= EPS > 0 afterwards
#pragma unroll
        for (int i = 1; i <= ORDER; ++i) {
            float acc = rr[i];
#pragma unroll
            for (int j = 1; j < i; ++j) acc -= a[j] * rr[i - j];
            float k = acc / e;
#pragma unroll
            for (int j = 1; 2 * j < i; ++j) {   // pairwise in-place update
                float aj = a[j], aij = a[i - j];
                a[j]     = aj  - k * aij;
                a[i - j] = aij - k * aj;
            }
            if ((i & 1) == 0) {
                int m = i >> 1;
                a[m] = a[m] - k * a[m];
            }
            a[i] = k;
            e = fmaxf(e * (1.f - k * k), LPC_EPS);
        }

        // coeffs into row head (partial slot 0 already consumed by this lane)
        float* cs = &xs[t * SX];
#pragma unroll
        for (int m = 0; m < 4; ++m)
            *(float4*)(cs + 4 * m) =
                make_float4(a[4 * m], a[4 * m + 1], a[4 * m + 2], a[4 * m + 3]);
        cs[16] = a[16];
    }
    __syncthreads();

    // ---- coeff read: 8 lanes of a frame hit the same address -> broadcast ----
    float a[ORDER + 1];
    {
        const float* cs = &xs[fi * SX];
#pragma unroll
        for (int m = 0; m < 4; ++m) {
            float4 v = *(const float4*)(cs + 4 * m);
            a[4 * m + 0] = v.x; a[4 * m + 1] = v.y;
            a[4 * m + 2] = v.z; a[4 * m + 3] = v.w;
        }
        a[16] = cs[16];
    }

    // ---- FIR: res[sbase+n] = sum_k a[k]*W[16+n-k]; in-place row write.
    //      (coeff reads precede these writes in wave program order; rows are
    //      frame-private -> no barrier needed here) ----
#pragma unroll
    for (int m = 0; m < SEG / 4; ++m) {
        float o[4];
#pragma unroll
        for (int i = 0; i < 4; ++i) {
            int n = 4 * m + i;
            float s = 0.f;
#pragma unroll
            for (int k = 0; k <= ORDER; ++k) {
                s = fmaf(a[k], W[16 + n - k], s);   // indices compile-time
            }
            o[i] = s;
        }
        *(float4*)(&xs[fi * SX + sbase + 4 * m]) = make_float4(o[0], o[1], o[2], o[3]);
    }
    __syncthreads();

    // ---- stage out: fully coalesced ----
#pragma unroll
    for (int it = 0; it < QPB; ++it) {
        int p = it * BS + t;
        int f = p / 40;
        int off = (p - f * 40) * 4;
        float4 v = *(const float4*)(&xs[f * SX + off]);
        *(float4*)(out + base + 4 * p) = v;
    }
}

extern "C" void kernel_launch(void* const* d_in, const int* in_sizes, int n_in,
                              void* d_out, int out_size, void* d_ws, size_t ws_size,
                              hipStream_t stream) {
    const float* x = (const float*)d_in[0];
    float* out = (float*)d_out;
    int total = in_sizes[0];                 // 20,480,000 = 128,000 frames
    int n_frames = total / FRAME;
    int n_blocks = n_frames / NF;            // 4000 (exact for this problem shape)
    lpc_fused<<<n_blocks, BS, 0, stream>>>(x, out);
}